// Round 14
// baseline (1032.089 us; speedup 1.0000x reference)
//
#include <hip/hip_runtime.h>
#include <hip/hip_fp16.h>

constexpr int B = 2, H = 12, S = 2048, D = 64;
constexpr int TQ = 16;
constexpr int NBLK_Q = S / TQ;                    // 128
constexpr int CMC = 32;                           // candidate cap per (row, 128-key cell)
constexpr int NCELL = 16;                         // 4 ks-sections x 4 waves
constexpr int SLOTS = NCELL * CMC;                // 512 slots per row
constexpr size_t BHSD = (size_t)B * H * S * D;    // 3,145,728
constexpr size_t RR = (size_t)B * H * S;          // 49,152 rows

using f16x8 = _Float16 __attribute__((ext_vector_type(8)));
using f16x4 = _Float16 __attribute__((ext_vector_type(4)));
using f32x4 = float   __attribute__((ext_vector_type(4)));

__device__ __forceinline__ int swz2(int q, int k) {
    return k ^ ((((k >> 6) ^ q) & 7) << 3);
}

// ---- pre-pass: X fp32 [bh][r][d] -> f16 MFMA-tiled (t*1024 + c2*512 + (grp*16+row)*8 + e) ----
template <bool SCALED>
__global__ __launch_bounds__(256)
void cvt_tiled_kernel(const float* __restrict__ X, const float* __restrict__ scale,
                      _Float16* __restrict__ Xh) {
    const int bh   = blockIdx.x >> 6;
    const int t    = (blockIdx.x & 63) * 2 + (threadIdx.x >> 7);
    const int f    = threadIdx.x & 127;           // c2*64 + grp*16 + row
    const int c2   = f >> 6, grp = (f >> 4) & 3, row = f & 15;
    const size_t bhSD = (size_t)bh * S * D;
    float sc = 1.0f;
    if constexpr (SCALED) sc = __expf(scale[bh % H]) * 0.125f;
    const float* src = X + bhSD + (size_t)(t * 16 + row) * D + c2 * 32 + grp * 8;
    const float4 x0 = *reinterpret_cast<const float4*>(src);
    const float4 x1 = *reinterpret_cast<const float4*>(src + 4);
    f16x8 y;
    y[0] = (_Float16)(x0.x * sc); y[1] = (_Float16)(x0.y * sc);
    y[2] = (_Float16)(x0.z * sc); y[3] = (_Float16)(x0.w * sc);
    y[4] = (_Float16)(x1.x * sc); y[5] = (_Float16)(x1.y * sc);
    y[6] = (_Float16)(x1.z * sc); y[7] = (_Float16)(x1.w * sc);
    *reinterpret_cast<f16x8*>(Xh + bhSD + (size_t)t * 1024 + f * 8) = y;
}

// ---- pre-pass (fused-fallback tier only): V fp32 [bh][k][d] -> f16 tiled transposed ----
__global__ __launch_bounds__(256)
void tr_v_kernel(const float* __restrict__ V, _Float16* __restrict__ Vt) {
    const int bh = blockIdx.x >> 6;
    const int c  = blockIdx.x & 63;
    const int f  = threadIdx.x;
    const int dh = f >> 7, n2 = (f >> 6) & 1, grp = (f >> 4) & 3, row = f & 15;
    const int d  = dh * 32 + n2 * 16 + row;
    const size_t bhSD = (size_t)bh * S * D;
    const float* src = V + bhSD + (size_t)(c * 32 + grp * 8) * D + d;
    f16x8 y;
    #pragma unroll
    for (int e = 0; e < 8; ++e) y[e] = (_Float16)src[e * D];
    *reinterpret_cast<f16x8*>(Vt + bhSD + (size_t)c * 2048 + f * 8) = y;
}

// ============ kernel 1: QK^T tiles + in-register candidate extraction ============
// Per (bh, qt, ks) block; wave w covers 128 keys = cell ks*4+w. NO score materialization.
// Superset rule: within a cell, {z > cellmax-1} contains all global candidates there.
__global__ __launch_bounds__(256, 4)
void qk_cand_kernel(const _Float16* __restrict__ Qht, const _Float16* __restrict__ Kht,
                    const float* __restrict__ mask, float* __restrict__ cval,
                    unsigned short* __restrict__ cidx, unsigned* __restrict__ ccnt,
                    unsigned* __restrict__ flg)
{
    const int tid  = threadIdx.x;
    const int lane = tid & 63;
    const int w    = tid >> 6;              // wave 0..3
    const int row  = lane & 15;
    const int grp  = lane >> 4;
    int idx = blockIdx.x;
    const int ks = idx & 3;  idx >>= 2;
    const int qt = idx & 127; idx >>= 7;
    const int bh = idx;
    const int b  = bh / H;
    const size_t bhSD = (size_t)bh * S * D;
    const float* mrow = mask + (size_t)b * S;

    const _Float16* qsrc = Qht + bhSD + (size_t)qt * 1024 + lane * 8;
    const f16x8 qa0 = *reinterpret_cast<const f16x8*>(qsrc);
    const f16x8 qa1 = *reinterpret_cast<const f16x8*>(qsrc + 512);

    float z[8][4];                          // this thread's 32 scores (q=row, 32 keys)
    const int t0 = ks * 32 + w * 8;
    #pragma unroll
    for (int i = 0; i < 8; ++i) {
        const _Float16* kp = Kht + bhSD + (size_t)(t0 + i) * 1024 + lane * 8;
        const f16x8 kb0 = *reinterpret_cast<const f16x8*>(kp);
        const f16x8 kb1 = *reinterpret_cast<const f16x8*>(kp + 512);
        f32x4 acc = {0.f, 0.f, 0.f, 0.f};
        acc = __builtin_amdgcn_mfma_f32_16x16x32_f16(kb0, qa0, acc, 0, 0, 0);
        acc = __builtin_amdgcn_mfma_f32_16x16x32_f16(kb1, qa1, acc, 0, 0, 0);
        const int key0 = (t0 + i) * 16;
        const float4 msk = *reinterpret_cast<const float4*>(mrow + key0 + grp * 4);
        #pragma unroll
        for (int r = 0; r < 4; ++r)
            z[i][r] = acc[r] + fmaf((&msk.x)[r], 1.0e9f, -1.0e9f);   // 0 if mask=1 else -1e9
    }

    // per-row cell max (reduce across the 4 grp-lanes holding the same q=row)
    float m = z[0][0];
    #pragma unroll
    for (int i = 0; i < 8; ++i)
        #pragma unroll
        for (int r = 0; r < 4; ++r) m = fmaxf(m, z[i][r]);
    m = fmaxf(m, __shfl_xor(m, 16));
    m = fmaxf(m, __shfl_xor(m, 32));
    const float thr = m - 1.0f;             // cell-conservative candidate threshold

    int c = 0;
    #pragma unroll
    for (int i = 0; i < 8; ++i)
        #pragma unroll
        for (int r = 0; r < 4; ++r) c += (z[i][r] > thr) ? 1 : 0;

    // deterministic slot assignment: prefix over grp lanes of the same row
    const int c0 = __shfl(c, row);
    const int c1 = __shfl(c, row + 16);
    const int c2 = __shfl(c, row + 32);
    const int c3 = __shfl(c, row + 48);
    const int base  = (grp > 0 ? c0 : 0) + (grp > 1 ? c1 : 0) + (grp > 2 ? c2 : 0);
    const int total = c0 + c1 + c2 + c3;

    const int grow = bh * S + qt * 16 + row;
    const int cell = ks * 4 + w;
    if (grp == 0) {
        ccnt[(size_t)grow * NCELL + cell] = (unsigned)(total < CMC ? total : CMC);
        if (total > CMC) flg[grow] = 1u;    // benign same-value race across cells
    }
    float* cvr = cval + (size_t)grow * SLOTS + cell * CMC;
    unsigned short* cir = cidx + (size_t)grow * SLOTS + cell * CMC;
    int o = base;
    #pragma unroll
    for (int i = 0; i < 8; ++i)
        #pragma unroll
        for (int r = 0; r < 4; ++r) {
            const float zz = z[i][r];
            if (zz > thr) {
                if (o < CMC) {
                    cvr[o] = zz;
                    cir[o] = (unsigned short)((t0 + i) * 16 + grp * 4 + r);
                }
                ++o;
            }
        }
}

// ============ kernel 2: exact tau via Newton over the candidate superset ============
// One wave per row. 4 lanes per cell, <=8 slots/lane. Newton over superset == exact tau
// (elements <= gmax-1 contribute 0 for all tau >= gmax-1; iterates stay in that region).
__global__ __launch_bounds__(256, 4)
void tau_kernel(const float* __restrict__ cval, const unsigned* __restrict__ ccnt,
                const unsigned* __restrict__ flg, float* __restrict__ tauv)
{
    const int tid = threadIdx.x, lane = tid & 63, w = tid >> 6;
    const int row = blockIdx.x * 4 + w;
    if (flg[row]) return;                   // handled by sv fallback
    const int cell = lane >> 2, sub = lane & 3;
    const int cc = (int)ccnt[(size_t)row * NCELL + cell];
    const float* cv = cval + (size_t)row * SLOTS + cell * CMC;
    float v[8];
    #pragma unroll
    for (int k = 0; k < 8; ++k) {
        const int j = sub + 4 * k;
        v[k] = (j < cc) ? cv[j] : -1.0e30f;
    }
    float m = v[0];
    #pragma unroll
    for (int k = 1; k < 8; ++k) m = fmaxf(m, v[k]);
    #pragma unroll
    for (int off = 32; off >= 1; off >>= 1) m = fmaxf(m, __shfl_xor(m, off));
    float t = m - 1.0f;                     // gmax is always a candidate -> true row max
    #pragma unroll 1
    for (int it = 0; it < 24; ++it) {
        float s = 0.f, c = 0.f;
        #pragma unroll
        for (int k = 0; k < 8; ++k) {
            const float d = v[k] - t;
            s += fmaxf(d, 0.f);
            c += (d > 0.f ? 1.f : 0.f);
        }
        #pragma unroll
        for (int off = 32; off >= 1; off >>= 1) {
            s += __shfl_xor(s, off);
            c += __shfl_xor(c, off);
        }
        const float tn = t + (s - 1.0f) / c;
        if (!(tn > t)) break;               // support stable -> exact
        t = tn;
    }
    if (lane == 0) tauv[row] = t;
}

// ============ kernel 3: sparse PV — out[q] = sum_cand max(z-tau,0) * V[k] ============
// One wave per row; lane = d. Candidate scan is wave-uniform; V gathers are coalesced
// 256B rows, L2-resident per head. Flagged rows: exact f32 full-row recompute.
__global__ __launch_bounds__(256, 4)
void sv_kernel(const float* __restrict__ cval, const unsigned short* __restrict__ cidx,
               const unsigned* __restrict__ ccnt, const unsigned* __restrict__ flg,
               const float* __restrict__ tauv,
               const float* __restrict__ Q, const float* __restrict__ K,
               const float* __restrict__ V, const float* __restrict__ mask,
               const float* __restrict__ scale, float* __restrict__ out)
{
    __shared__ float qrow_sh[4][64];
    __shared__ float facc_sh[4][64];
    const int tid = threadIdx.x, lane = tid & 63, w = tid >> 6;
    const int row = blockIdx.x * 4 + w;
    const int bh = row >> 11, q = row & 2047;
    const size_t bhSD = (size_t)bh * S * D;

    if (!flg[row]) {
        const float t = tauv[row];
        const float* cv = cval + (size_t)row * SLOTS;
        const unsigned short* ci = cidx + (size_t)row * SLOTS;
        const unsigned* cc = ccnt + (size_t)row * NCELL;
        float acc = 0.f;
        #pragma unroll 1
        for (int cell = 0; cell < NCELL; ++cell) {
            const int n = (int)cc[cell];
            const float* cvc = cv + cell * CMC;
            const unsigned short* cic = ci + cell * CMC;
            #pragma unroll 1
            for (int j = 0; j < n; ++j) {
                const float p = cvc[j] - t;         // wave-uniform
                if (p > 0.f) {
                    const int k = (int)cic[j];
                    acc = fmaf(p, V[bhSD + (size_t)k * D + lane], acc);
                }
            }
        }
        out[bhSD + (size_t)q * D + lane] = acc;
    } else {
        // rare exact fallback: recompute the whole row in f32 (lane owns 32 keys)
        const int h = bh % H;
        const float sc = __expf(scale[h]) * 0.125f;
        const float* mrow = mask + (size_t)(bh / H) * S;
        qrow_sh[w][lane] = Q[bhSD + (size_t)q * D + lane] * sc;
        facc_sh[w][lane] = 0.f;
        asm volatile("s_waitcnt lgkmcnt(0)" ::: "memory");
        __builtin_amdgcn_sched_barrier(0);
        float z[32];
        #pragma unroll
        for (int i = 0; i < 32; ++i) {
            const int k = lane + (i << 6);
            const float* kr = K + bhSD + (size_t)k * D;
            float s = 0.f;
            #pragma unroll
            for (int d4 = 0; d4 < 16; ++d4) {
                const float4 kk = *reinterpret_cast<const float4*>(kr + d4 * 4);
                s += qrow_sh[w][d4 * 4 + 0] * kk.x + qrow_sh[w][d4 * 4 + 1] * kk.y
                   + qrow_sh[w][d4 * 4 + 2] * kk.z + qrow_sh[w][d4 * 4 + 3] * kk.w;
            }
            z[i] = s + fmaf(mrow[k], 1.0e9f, -1.0e9f);
        }
        float m = z[0];
        #pragma unroll
        for (int i = 1; i < 32; ++i) m = fmaxf(m, z[i]);
        #pragma unroll
        for (int off = 32; off >= 1; off >>= 1) m = fmaxf(m, __shfl_xor(m, off));
        float t = m - 1.0f;
        #pragma unroll 1
        for (int it = 0; it < 48; ++it) {
            float s = 0.f, c = 0.f;
            #pragma unroll
            for (int i = 0; i < 32; ++i) {
                const float d = z[i] - t;
                s += fmaxf(d, 0.f);
                c += (d > 0.f ? 1.f : 0.f);
            }
            #pragma unroll
            for (int off = 32; off >= 1; off >>= 1) {
                s += __shfl_xor(s, off);
                c += __shfl_xor(c, off);
            }
            const float tn = t + (s - 1.0f) / c;
            if (!(tn > t)) break;
            t = tn;
        }
        #pragma unroll
        for (int i = 0; i < 32; ++i) {
            const float p = z[i] - t;
            if (p > 0.f) {
                const int k = lane + (i << 6);
                const float* vr = V + bhSD + (size_t)k * D;
                #pragma unroll
                for (int d = 0; d < 64; ++d)
                    atomicAdd(&facc_sh[w][d], p * vr[d]);
            }
        }
        asm volatile("s_waitcnt lgkmcnt(0) vmcnt(0)" ::: "memory");
        __builtin_amdgcn_sched_barrier(0);
        out[bhSD + (size_t)q * D + lane] = facc_sh[w][lane];
    }
}

// ================= fallback tier: r7 fused kernel (measured 146 us) =================
template <bool PRE>
__global__ __launch_bounds__(1024, 8)
void sparsemax_attn_kernel(const float* __restrict__ Q, const float* __restrict__ K,
                           const float* __restrict__ V, const float* __restrict__ mask,
                           const float* __restrict__ scale, float* __restrict__ out,
                           const _Float16* __restrict__ Kh, const _Float16* __restrict__ Vt)
{
    __shared__ alignas(16) _Float16 s_sh[TQ * 2048];
    __shared__ alignas(16) float    madd_sh[S];
    __shared__ float tau_s[TQ];

    const int tid  = threadIdx.x;
    const int lane = tid & 63;
    const int w    = tid >> 6;
    const int row  = lane & 15;
    const int grp  = lane >> 4;
    const int bh   = blockIdx.x / NBLK_Q;
    const int qt   = blockIdx.x - bh * NBLK_Q;
    const int b    = bh / H;
    const int h    = bh - b * H;
    const int q0   = qt * TQ;
    const size_t bhSD = (size_t)bh * S * D;
    const float* mrow = mask + (size_t)b * S;
    const float  sc   = __expf(scale[h]) * 0.125f;

    madd_sh[tid]        = (1.0f - mrow[tid])        * -1.0e9f;
    madd_sh[tid + 1024] = (1.0f - mrow[tid + 1024]) * -1.0e9f;

    f16x8 qa[2];
    {
        const float* qr = Q + bhSD + (size_t)(q0 + row) * D + grp * 8;
        #pragma unroll
        for (int c = 0; c < 2; ++c) {
            const float4 x0 = *reinterpret_cast<const float4*>(qr + c * 32);
            const float4 x1 = *reinterpret_cast<const float4*>(qr + c * 32 + 4);
            qa[c][0] = (_Float16)(x0.x * sc); qa[c][1] = (_Float16)(x0.y * sc);
            qa[c][2] = (_Float16)(x0.z * sc); qa[c][3] = (_Float16)(x0.w * sc);
            qa[c][4] = (_Float16)(x1.x * sc); qa[c][5] = (_Float16)(x1.y * sc);
            qa[c][6] = (_Float16)(x1.z * sc); qa[c][7] = (_Float16)(x1.w * sc);
        }
    }
    __syncthreads();

    if constexpr (PRE) {
        const _Float16* ksrc = Kh + bhSD + (size_t)(w * 8) * 1024 + lane * 8;
        f16x8 ka0 = *reinterpret_cast<const f16x8*>(ksrc);
        f16x8 ka1 = *reinterpret_cast<const f16x8*>(ksrc + 512);
        #pragma unroll
        for (int i = 0; i < 8; ++i) {
            f16x8 nb0, nb1;
            if (i < 7) {
                nb0 = *reinterpret_cast<const f16x8*>(ksrc + (i + 1) * 1024);
                nb1 = *reinterpret_cast<const f16x8*>(ksrc + (i + 1) * 1024 + 512);
            }
            f32x4 acc = {0.f, 0.f, 0.f, 0.f};
            acc = __builtin_amdgcn_mfma_f32_16x16x32_f16(ka0, qa[0], acc, 0, 0, 0);
            acc = __builtin_amdgcn_mfma_f32_16x16x32_f16(ka1, qa[1], acc, 0, 0, 0);
            const int key0 = (w * 8 + i) * 16;
            const float4 ma = *reinterpret_cast<const float4*>(madd_sh + key0 + grp * 4);
            f16x4 st;
            #pragma unroll
            for (int r = 0; r < 4; ++r)
                st[r] = (_Float16)fmaxf(acc[r] + (&ma.x)[r], -60000.0f);
            *reinterpret_cast<f16x4*>(&s_sh[row * 2048 + swz2(row, key0 + grp * 4)]) = st;
            ka0 = nb0; ka1 = nb1;
        }
    } else {
        for (int t = w * 8; t < w * 8 + 8; ++t) {
            const int key0 = t * 16;
            const float* kp = K + bhSD + (size_t)(key0 + row) * D + grp * 8;
            f16x8 kb0, kb1;
            #pragma unroll
            for (int c = 0; c < 2; ++c) {
                const float4 x0 = *reinterpret_cast<const float4*>(kp + c * 32);
                const float4 x1 = *reinterpret_cast<const float4*>(kp + c * 32 + 4);
                f16x8& kb = c ? kb1 : kb0;
                kb[0] = (_Float16)x0.x; kb[1] = (_Float16)x0.y;
                kb[2] = (_Float16)x0.z; kb[3] = (_Float16)x0.w;
                kb[4] = (_Float16)x1.x; kb[5] = (_Float16)x1.y;
                kb[6] = (_Float16)x1.z; kb[7] = (_Float16)x1.w;
            }
            f32x4 acc = {0.f, 0.f, 0.f, 0.f};
            acc = __builtin_amdgcn_mfma_f32_16x16x32_f16(kb0, qa[0], acc, 0, 0, 0);
            acc = __builtin_amdgcn_mfma_f32_16x16x32_f16(kb1, qa[1], acc, 0, 0, 0);
            const float4 ma = *reinterpret_cast<const float4*>(madd_sh + key0 + grp * 4);
            f16x4 st;
            #pragma unroll
            for (int r = 0; r < 4; ++r)
                st[r] = (_Float16)fmaxf(acc[r] + (&ma.x)[r], -60000.0f);
            *reinterpret_cast<f16x4*>(&s_sh[row * 2048 + swz2(row, key0 + grp * 4)]) = st;
        }
    }
    __syncthreads();

    {
        const int q = w;
        const _Float16* zrow = &s_sh[q * 2048];
        const f16x8 zv0 = *reinterpret_cast<const f16x8*>(&zrow[swz2(q, lane * 32 +  0)]);
        const f16x8 zv1 = *reinterpret_cast<const f16x8*>(&zrow[swz2(q, lane * 32 +  8)]);
        const f16x8 zv2 = *reinterpret_cast<const f16x8*>(&zrow[swz2(q, lane * 32 + 16)]);
        const f16x8 zv3 = *reinterpret_cast<const f16x8*>(&zrow[swz2(q, lane * 32 + 24)]);
        const f16x8 m8 = __builtin_elementwise_max(__builtin_elementwise_max(zv0, zv1),
                                                   __builtin_elementwise_max(zv2, zv3));
        float m = (float)m8[0];
        #pragma unroll
        for (int e = 1; e < 8; ++e) m = fmaxf(m, (float)m8[e]);
        #pragma unroll
        for (int off = 32; off >= 1; off >>= 1) m = fmaxf(m, __shfl_xor(m, off));
        const float thr = m - 1.0f;
        float c0 = -1.0e30f, c1 = -1.0e30f, c2 = -1.0e30f;
        int lc = 0;
#define EXTRACT8(ZV) { _Pragma("unroll") for (int e = 0; e < 8; ++e) { \
            const float zz = (float)(ZV)[e]; \
            if (zz > thr) { \
                c2 = (lc == 2) ? zz : c2; \
                c1 = (lc == 1) ? zz : c1; \
                c0 = (lc == 0) ? zz : c0; \
                ++lc; } } }
        EXTRACT8(zv0) EXTRACT8(zv1) EXTRACT8(zv2) EXTRACT8(zv3)
#undef EXTRACT8
        float tau = thr;
        if (__ballot(lc > 3) == 0ULL) {
            #pragma unroll 1
            for (int it = 0; it < 24; ++it) {
                const float d0 = c0 - tau, d1 = c1 - tau, d2 = c2 - tau;
                float s = fmaxf(d0, 0.f) + fmaxf(d1, 0.f) + fmaxf(d2, 0.f);
                float c = (d0 > 0.f ? 1.f : 0.f) + (d1 > 0.f ? 1.f : 0.f) + (d2 > 0.f ? 1.f : 0.f);
                #pragma unroll
                for (int off = 32; off >= 1; off >>= 1) {
                    s += __shfl_xor(s, off);
                    c += __shfl_xor(c, off);
                }
                const float tn = tau + (s - 1.0f) / c;
                if (!(tn > tau)) break;
                tau = tn;
            }
        } else {
            #pragma unroll 1
            for (int it = 0; it < 32; ++it) {
                float s = 0.f, c = 0.f;
#define ACC8(ZV) { _Pragma("unroll") for (int e = 0; e < 8; ++e) { \
                const float d = (float)(ZV)[e] - tau; \
                s += fmaxf(d, 0.f); c += (d > 0.f ? 1.f : 0.f); } }
                ACC8(zv0) ACC8(zv1) ACC8(zv2) ACC8(zv3)
#undef ACC8
                #pragma unroll
                for (int off = 32; off >= 1; off >>= 1) {
                    s += __shfl_xor(s, off);
                    c += __shfl_xor(c, off);
                }
                const float tn = tau + (s - 1.0f) / c;
                if (!(tn > tau)) break;
                tau = tn;
            }
        }
        if (lane == 0) tau_s[q] = tau;
    }
    __syncthreads();

    const float tau_row = tau_s[row];
    f16x8 t8;
    {
        const _Float16 th = (_Float16)tau_row;
        #pragma unroll
        for (int e = 0; e < 8; ++e) t8[e] = th;
    }
    f32x4 o[4] = {{0.f,0.f,0.f,0.f},{0.f,0.f,0.f,0.f},{0.f,0.f,0.f,0.f},{0.f,0.f,0.f,0.f}};
    if constexpr (PRE) {
        const _Float16* vsrc = Vt + bhSD + (size_t)w * 8192 + lane * 8;
        f16x8 va0 = *reinterpret_cast<const f16x8*>(vsrc);
        f16x8 va1 = *reinterpret_cast<const f16x8*>(vsrc + 512);
        #pragma unroll
        for (int hc = 0; hc < 8; ++hc) {
            f16x8 nb0, nb1;
            if (hc < 7) {
                nb0 = *reinterpret_cast<const f16x8*>(vsrc + (hc + 1) * 1024);
                nb1 = *reinterpret_cast<const f16x8*>(vsrc + (hc + 1) * 1024 + 512);
            }
            const int k0 = (w * 4 + (hc >> 1)) * 32;
            const f16x8 zv = *reinterpret_cast<const f16x8*>(
                &s_sh[row * 2048 + swz2(row, k0 + grp * 8)]);
            const f16x8 pa = __builtin_elementwise_max(zv - t8, (f16x8)(_Float16)0.0f);
            const int nb = (hc & 1) * 2;
            o[nb]     = __builtin_amdgcn_mfma_f32_16x16x32_f16(pa, va0, o[nb],     0, 0, 0);
            o[nb + 1] = __builtin_amdgcn_mfma_f32_16x16x32_f16(pa, va1, o[nb + 1], 0, 0, 0);
            va0 = nb0; va1 = nb1;
        }
    } else {
        for (int c = w * 4; c < w * 4 + 4; ++c) {
            const int k0 = c * 32;
            const f16x8 zv = *reinterpret_cast<const f16x8*>(
                &s_sh[row * 2048 + swz2(row, k0 + grp * 8)]);
            const f16x8 pa2 = __builtin_elementwise_max(zv - t8, (f16x8)(_Float16)0.0f);
            #pragma unroll
            for (int n = 0; n < 4; ++n) {
                f16x8 vb;
                #pragma unroll
                for (int j = 0; j < 8; ++j)
                    vb[j] = (_Float16)V[bhSD + (size_t)(k0 + grp * 8 + j) * D + n * 16 + row];
                o[n] = __builtin_amdgcn_mfma_f32_16x16x32_f16(pa2, vb, o[n], 0, 0, 0);
            }
        }
    }
    __syncthreads();

    float* red = reinterpret_cast<float*>(s_sh);
    #pragma unroll
    for (int n = 0; n < 4; ++n)
        #pragma unroll
        for (int r = 0; r < 4; ++r)
            red[w * 1024 + (grp * 4 + r) * 64 + n * 16 + row] = o[n][r];
    __syncthreads();

    {
        const int q = tid >> 6;
        const int d = tid & 63;
        float sum = 0.f;
        #pragma unroll
        for (int p = 0; p < 16; ++p)
            sum += red[p * 1024 + q * 64 + d];
        out[bhSD + (size_t)(q0 + q) * D + d] = sum;
    }
}

extern "C" void kernel_launch(void* const* d_in, const int* in_sizes, int n_in,
                              void* d_out, int out_size, void* d_ws, size_t ws_size,
                              hipStream_t stream) {
    const float* Q     = (const float*)d_in[0];
    const float* K     = (const float*)d_in[1];
    const float* V     = (const float*)d_in[2];
    const float* mask  = (const float*)d_in[3];
    const float* scale = (const float*)d_in[4];
    float* out = (float*)d_out;

    const int BH = B * H;
    const size_t need_sparse = 2 * BHSD * sizeof(_Float16)   // Qht, Kht
                             + RR * SLOTS * sizeof(float)    // cand values
                             + RR * SLOTS * sizeof(unsigned short)  // cand indices
                             + RR * NCELL * sizeof(unsigned) // per-cell counts
                             + RR * sizeof(unsigned)         // overflow flags
                             + RR * sizeof(float);           // tau
    const size_t need_fused  = 2 * BHSD * sizeof(_Float16);

    if (ws_size >= need_sparse) {
        char* p = (char*)d_ws;
        _Float16* Qht = (_Float16*)p;        p += BHSD * sizeof(_Float16);
        _Float16* Kht = (_Float16*)p;        p += BHSD * sizeof(_Float16);
        float* cval = (float*)p;             p += RR * SLOTS * sizeof(float);
        unsigned short* cidx = (unsigned short*)p; p += RR * SLOTS * sizeof(unsigned short);
        unsigned* ccnt = (unsigned*)p;       p += RR * NCELL * sizeof(unsigned);
        unsigned* flg = (unsigned*)p;        p += RR * sizeof(unsigned);
        float* tau = (float*)p;
        hipMemsetAsync(flg, 0, RR * sizeof(unsigned), stream);
        cvt_tiled_kernel<true ><<<dim3(BH * 64), dim3(256), 0, stream>>>(Q, scale, Qht);
        cvt_tiled_kernel<false><<<dim3(BH * 64), dim3(256), 0, stream>>>(K, scale, Kht);
        qk_cand_kernel<<<dim3(BH * 128 * 4), dim3(256), 0, stream>>>(
            Qht, Kht, mask, cval, cidx, ccnt, flg);
        tau_kernel<<<dim3((unsigned)(RR / 4)), dim3(256), 0, stream>>>(cval, ccnt, flg, tau);
        sv_kernel<<<dim3((unsigned)(RR / 4)), dim3(256), 0, stream>>>(
            cval, cidx, ccnt, flg, tau, Q, K, V, mask, scale, out);
    } else if (ws_size >= need_fused) {
        _Float16* Kh = (_Float16*)d_ws;
        _Float16* Vt = Kh + BHSD;
        cvt_tiled_kernel<false><<<dim3(BH * 64), dim3(256), 0, stream>>>(K, scale, Kh);
        tr_v_kernel<<<dim3(BH * 64), dim3(256), 0, stream>>>(V, Vt);
        sparsemax_attn_kernel<true><<<dim3(BH * NBLK_Q), dim3(1024), 0, stream>>>(
            Q, K, V, mask, scale, out, Kh, Vt);
    } else {
        sparsemax_attn_kernel<false><<<dim3(BH * NBLK_Q), dim3(1024), 0, stream>>>(
            Q, K, V, mask, scale, out, nullptr, nullptr);
    }
}

// Round 15
// 836.709 us; speedup vs baseline: 1.2335x; 1.2335x over previous
//
#include <hip/hip_runtime.h>
#include <hip/hip_fp16.h>

constexpr int B = 2, H = 12, S = 2048, D = 64;
constexpr int TQ = 16;
constexpr int NBLK_Q = S / TQ;                    // 128
constexpr int CMC = 32;                           // candidate cap per (row, 128-key cell)
constexpr int NCELL = 16;                         // 16 cells of 128 keys
constexpr size_t BHSD = (size_t)B * H * S * D;    // 3,145,728

using f16x8 = _Float16 __attribute__((ext_vector_type(8)));
using f16x4 = _Float16 __attribute__((ext_vector_type(4)));
using f32x4 = float   __attribute__((ext_vector_type(4)));
using u16x8 = unsigned short __attribute__((ext_vector_type(8)));

// ---- pre-pass: X fp32 [bh][r][d] -> f16 MFMA-tiled (t*1024 + c2*512 + (grp*16+row)*8 + e) ----
template <bool SCALED>
__global__ __launch_bounds__(256)
void cvt_tiled_kernel(const float* __restrict__ X, const float* __restrict__ scale,
                      _Float16* __restrict__ Xh) {
    const int bh   = blockIdx.x >> 6;
    const int t    = (blockIdx.x & 63) * 2 + (threadIdx.x >> 7);
    const int f    = threadIdx.x & 127;           // c2*64 + grp*16 + row
    const int c2   = f >> 6, grp = (f >> 4) & 3, row = f & 15;
    const size_t bhSD = (size_t)bh * S * D;
    float sc = 1.0f;
    if constexpr (SCALED) sc = __expf(scale[bh % H]) * 0.125f;
    const float* src = X + bhSD + (size_t)(t * 16 + row) * D + c2 * 32 + grp * 8;
    const float4 x0 = *reinterpret_cast<const float4*>(src);
    const float4 x1 = *reinterpret_cast<const float4*>(src + 4);
    f16x8 y;
    y[0] = (_Float16)(x0.x * sc); y[1] = (_Float16)(x0.y * sc);
    y[2] = (_Float16)(x0.z * sc); y[3] = (_Float16)(x0.w * sc);
    y[4] = (_Float16)(x1.x * sc); y[5] = (_Float16)(x1.y * sc);
    y[6] = (_Float16)(x1.z * sc); y[7] = (_Float16)(x1.w * sc);
    *reinterpret_cast<f16x8*>(Xh + bhSD + (size_t)t * 1024 + f * 8) = y;
}

// ============ fused candidate-sparse kernel: one block = (bh, 16-q-tile) ============
// Phase 1: QK^T via MFMA; per (row, 128-key cell) extract candidates {z > cellmax-1}
//          (superset of sparsemax support since tau* >= gmax-1 >= cellmax-1) into LDS.
// Phase 2: per-row exact Newton tau over the candidate superset (one b128 read/lane).
// Phase 3: compact p>0 survivors, short gather of f32 V rows (coalesced, L2-hot).
__global__ __launch_bounds__(256, 4)
void spmax_cand_kernel(const _Float16* __restrict__ Qht, const _Float16* __restrict__ Kht,
                       const float* __restrict__ mask,
                       const float* __restrict__ Q, const float* __restrict__ K,
                       const float* __restrict__ V, const float* __restrict__ scale,
                       float* __restrict__ out)
{
    __shared__ alignas(16) _Float16       cval_sh[TQ][NCELL][CMC];   // 16 KB
    __shared__ alignas(16) unsigned short cidx_sh[TQ][NCELL][CMC];   // 16 KB
    __shared__ int   ccnt_sh[TQ][NCELL];                             // 1 KB
    __shared__ int   flg_sh[TQ];
    __shared__ alignas(16) float comp_p[4][64];                      // 1 KB
    __shared__ unsigned short    comp_k[4][64];                      // 0.5 KB
    __shared__ float qrow_sh[4][64];                                 // fallback only
    __shared__ float facc_sh[4][64];

    const int tid  = threadIdx.x;
    const int lane = tid & 63;
    const int w    = tid >> 6;              // wave 0..3
    const int row  = lane & 15;
    const int grp  = lane >> 4;             // 0..3
    const int bh   = blockIdx.x >> 7;
    const int qt   = blockIdx.x & 127;
    const int b    = bh / H;
    const int h    = bh - b * H;
    const size_t bhSD = (size_t)bh * S * D;
    const float* mrow = mask + (size_t)b * S;

    if (tid < TQ) flg_sh[tid] = 0;

    // Q fragments (scale folded by prepass)
    const _Float16* qsrc = Qht + bhSD + (size_t)qt * 1024 + lane * 8;
    const f16x8 qa0 = *reinterpret_cast<const f16x8*>(qsrc);
    const f16x8 qa1 = *reinterpret_cast<const f16x8*>(qsrc + 512);
    __syncthreads();   // flg init visible

    // ---------------- Phase 1: MFMA + per-cell candidate extraction ----------------
    #pragma unroll 1
    for (int sec = 0; sec < 4; ++sec) {
        const int cell = w * 4 + sec;       // keys cell*128 .. cell*128+127
        const int t0 = cell * 8;
        float z[8][4];
        #pragma unroll
        for (int i = 0; i < 8; ++i) {
            const _Float16* kp = Kht + bhSD + (size_t)(t0 + i) * 1024 + lane * 8;
            const f16x8 kb0 = *reinterpret_cast<const f16x8*>(kp);
            const f16x8 kb1 = *reinterpret_cast<const f16x8*>(kp + 512);
            f32x4 acc = {0.f, 0.f, 0.f, 0.f};
            acc = __builtin_amdgcn_mfma_f32_16x16x32_f16(kb0, qa0, acc, 0, 0, 0);
            acc = __builtin_amdgcn_mfma_f32_16x16x32_f16(kb1, qa1, acc, 0, 0, 0);
            const int key0 = (t0 + i) * 16;
            const float4 msk = *reinterpret_cast<const float4*>(mrow + key0 + grp * 4);
            #pragma unroll
            for (int r = 0; r < 4; ++r)
                z[i][r] = fmaxf(acc[r] + fmaf((&msk.x)[r], 1.0e9f, -1.0e9f), -60000.0f);
        }
        // per-row cell max (reduce over the 4 grp-lanes of the same q=row)
        float m = z[0][0];
        #pragma unroll
        for (int i = 0; i < 8; ++i)
            #pragma unroll
            for (int r = 0; r < 4; ++r) m = fmaxf(m, z[i][r]);
        m = fmaxf(m, __shfl_xor(m, 16));
        m = fmaxf(m, __shfl_xor(m, 32));
        const float thr = m - 1.0f;

        int c = 0;
        #pragma unroll
        for (int i = 0; i < 8; ++i)
            #pragma unroll
            for (int r = 0; r < 4; ++r) c += (z[i][r] > thr) ? 1 : 0;

        const int c0 = __shfl(c, row);
        const int c1 = __shfl(c, row + 16);
        const int c2 = __shfl(c, row + 32);
        const int c3 = __shfl(c, row + 48);
        const int base  = (grp > 0 ? c0 : 0) + (grp > 1 ? c1 : 0) + (grp > 2 ? c2 : 0);
        const int total = c0 + c1 + c2 + c3;
        if (grp == 0) {
            ccnt_sh[row][cell] = total < CMC ? total : CMC;
            if (total > CMC) flg_sh[row] = 1;   // benign same-value race
        }
        int o = base;
        #pragma unroll
        for (int i = 0; i < 8; ++i)
            #pragma unroll
            for (int r = 0; r < 4; ++r) {
                const float zz = z[i][r];
                if (zz > thr) {
                    if (o < CMC) {
                        cval_sh[row][cell][o] = (_Float16)zz;
                        cidx_sh[row][cell][o] = (unsigned short)((t0 + i) * 16 + grp * 4 + r);
                    }
                    ++o;
                }
            }
    }
    __syncthreads();   // all cells of all rows complete

    // ---------------- Phase 2+3: per-row tau + sparse PV (wave w: rows w*4..w*4+3) ----
    #pragma unroll 1
    for (int rr = 0; rr < 4; ++rr) {
        const int r_ = w * 4 + rr;
        const int gq = qt * 16 + r_;
        bool fb = (flg_sh[r_] != 0);
        if (!fb) {
            // lane covers slots lane*8 .. lane*8+7 (one b128 read; cell = lane>>2)
            const int cell = lane >> 2;
            const int so   = (lane & 3) * 8;
            const f16x8 vv = *reinterpret_cast<const f16x8*>(&cval_sh[r_][cell][so]);
            const int cnt = ccnt_sh[r_][cell];
            float v[8];
            #pragma unroll
            for (int k = 0; k < 8; ++k)
                v[k] = (so + k < cnt) ? (float)vv[k] : -1.0e30f;
            float m = v[0];
            #pragma unroll
            for (int k = 1; k < 8; ++k) m = fmaxf(m, v[k]);
            #pragma unroll
            for (int off = 32; off >= 1; off >>= 1) m = fmaxf(m, __shfl_xor(m, off));
            float t = m - 1.0f;                 // gmax is in the candidate set
            #pragma unroll 1
            for (int it = 0; it < 24; ++it) {
                float s = 0.f, c = 0.f;
                #pragma unroll
                for (int k = 0; k < 8; ++k) {
                    const float d = v[k] - t;
                    s += fmaxf(d, 0.f);
                    c += (d > 0.f ? 1.f : 0.f);
                }
                #pragma unroll
                for (int off = 32; off >= 1; off >>= 1) {
                    s += __shfl_xor(s, off);
                    c += __shfl_xor(c, off);
                }
                const float tn = t + (s - 1.0f) / c;
                if (!(tn > t)) break;           // support stable -> exact
                t = tn;
            }
            // compact p>0 survivors into the wave's gather list
            const u16x8 iv = *reinterpret_cast<const u16x8*>(&cidx_sh[r_][cell][so]);
            float p[8];
            int myc = 0;
            #pragma unroll
            for (int k = 0; k < 8; ++k) {
                p[k] = v[k] - t;
                myc += (p[k] > 0.f) ? 1 : 0;
            }
            int inc = myc;
            #pragma unroll
            for (int off = 1; off < 64; off <<= 1) {
                const int tt = __shfl_up(inc, off);
                if (lane >= off) inc += tt;
            }
            const int nc = __shfl(inc, 63);
            if (nc <= 64) {
                int o = inc - myc;
                #pragma unroll
                for (int k = 0; k < 8; ++k)
                    if (p[k] > 0.f) { comp_p[w][o] = p[k]; comp_k[w][o] = iv[k]; ++o; }
                float acc = 0.f;
                const float* Vb = V + bhSD;
                int j = 0;
                #pragma unroll 1
                for (; j + 4 <= nc; j += 4) {
                    const float p0 = comp_p[w][j],     p1 = comp_p[w][j + 1];
                    const float p2 = comp_p[w][j + 2], p3 = comp_p[w][j + 3];
                    const int k0 = comp_k[w][j],     k1 = comp_k[w][j + 1];
                    const int k2 = comp_k[w][j + 2], k3 = comp_k[w][j + 3];
                    acc = fmaf(p0, Vb[(size_t)k0 * D + lane], acc);
                    acc = fmaf(p1, Vb[(size_t)k1 * D + lane], acc);
                    acc = fmaf(p2, Vb[(size_t)k2 * D + lane], acc);
                    acc = fmaf(p3, Vb[(size_t)k3 * D + lane], acc);
                }
                #pragma unroll 1
                for (; j < nc; ++j)
                    acc = fmaf(comp_p[w][j], Vb[(size_t)comp_k[w][j] * D + lane], acc);
                out[bhSD + (size_t)gq * D + lane] = acc;
            } else {
                fb = true;
            }
        }
        if (fb) {
            // exact f32 full-row fallback (dead on this data; correctness safety net)
            const float sc = __expf(scale[h]) * 0.125f;
            qrow_sh[w][lane] = Q[bhSD + (size_t)gq * D + lane] * sc;
            facc_sh[w][lane] = 0.f;
            asm volatile("s_waitcnt lgkmcnt(0)" ::: "memory");
            __builtin_amdgcn_sched_barrier(0);
            float z2[32];
            #pragma unroll
            for (int i = 0; i < 32; ++i) {
                const int k = lane + (i << 6);
                const float* kr = K + bhSD + (size_t)k * D;
                float s = 0.f;
                #pragma unroll
                for (int d4 = 0; d4 < 16; ++d4) {
                    const float4 kk = *reinterpret_cast<const float4*>(kr + d4 * 4);
                    s += qrow_sh[w][d4 * 4 + 0] * kk.x + qrow_sh[w][d4 * 4 + 1] * kk.y
                       + qrow_sh[w][d4 * 4 + 2] * kk.z + qrow_sh[w][d4 * 4 + 3] * kk.w;
                }
                z2[i] = s + fmaf(mrow[k], 1.0e9f, -1.0e9f);
            }
            float m = z2[0];
            #pragma unroll
            for (int i = 1; i < 32; ++i) m = fmaxf(m, z2[i]);
            #pragma unroll
            for (int off = 32; off >= 1; off >>= 1) m = fmaxf(m, __shfl_xor(m, off));
            float t = m - 1.0f;
            #pragma unroll 1
            for (int it = 0; it < 48; ++it) {
                float s = 0.f, c = 0.f;
                #pragma unroll
                for (int i = 0; i < 32; ++i) {
                    const float d = z2[i] - t;
                    s += fmaxf(d, 0.f);
                    c += (d > 0.f ? 1.f : 0.f);
                }
                #pragma unroll
                for (int off = 32; off >= 1; off >>= 1) {
                    s += __shfl_xor(s, off);
                    c += __shfl_xor(c, off);
                }
                const float tn = t + (s - 1.0f) / c;
                if (!(tn > t)) break;
                t = tn;
            }
            #pragma unroll
            for (int i = 0; i < 32; ++i) {
                const float p = z2[i] - t;
                if (p > 0.f) {
                    const int k = lane + (i << 6);
                    const float* vr = V + bhSD + (size_t)k * D;
                    #pragma unroll
                    for (int d = 0; d < 64; ++d)
                        atomicAdd(&facc_sh[w][d], p * vr[d]);
                }
            }
            asm volatile("s_waitcnt lgkmcnt(0) vmcnt(0)" ::: "memory");
            __builtin_amdgcn_sched_barrier(0);
            out[bhSD + (size_t)gq * D + lane] = facc_sh[w][lane];
        }
    }
}

// ================= fallback tier (tiny ws): fused kernel, raw-input path =================
__global__ __launch_bounds__(1024, 8)
void sparsemax_fused_fallback(const float* __restrict__ Q, const float* __restrict__ K,
                              const float* __restrict__ V, const float* __restrict__ mask,
                              const float* __restrict__ scale, float* __restrict__ out)
{
    __shared__ alignas(16) _Float16 s_sh[TQ * 2048];
    __shared__ alignas(16) float    madd_sh[S];
    __shared__ float tau_s[TQ];

    const int tid  = threadIdx.x;
    const int lane = tid & 63;
    const int w    = tid >> 6;
    const int row  = lane & 15;
    const int grp  = lane >> 4;
    const int bh   = blockIdx.x / NBLK_Q;
    const int qt   = blockIdx.x - bh * NBLK_Q;
    const int b    = bh / H;
    const int h    = bh - b * H;
    const int q0   = qt * TQ;
    const size_t bhSD = (size_t)bh * S * D;
    const float* mrow = mask + (size_t)b * S;
    const float  sc   = __expf(scale[h]) * 0.125f;

    madd_sh[tid]        = (1.0f - mrow[tid])        * -1.0e9f;
    madd_sh[tid + 1024] = (1.0f - mrow[tid + 1024]) * -1.0e9f;

    f16x8 qa[2];
    {
        const float* qr = Q + bhSD + (size_t)(q0 + row) * D + grp * 8;
        #pragma unroll
        for (int c = 0; c < 2; ++c) {
            const float4 x0 = *reinterpret_cast<const float4*>(qr + c * 32);
            const float4 x1 = *reinterpret_cast<const float4*>(qr + c * 32 + 4);
            qa[c][0] = (_Float16)(x0.x * sc); qa[c][1] = (_Float16)(x0.y * sc);
            qa[c][2] = (_Float16)(x0.z * sc); qa[c][3] = (_Float16)(x0.w * sc);
            qa[c][4] = (_Float16)(x1.x * sc); qa[c][5] = (_Float16)(x1.y * sc);
            qa[c][6] = (_Float16)(x1.z * sc); qa[c][7] = (_Float16)(x1.w * sc);
        }
    }
    __syncthreads();

    auto swz2l = [] __device__ (int q, int k) { return k ^ ((((k >> 6) ^ q) & 7) << 3); };

    for (int t = w * 8; t < w * 8 + 8; ++t) {
        const int key0 = t * 16;
        const float* kp = K + bhSD + (size_t)(key0 + row) * D + grp * 8;
        f16x8 kb0, kb1;
        #pragma unroll
        for (int c = 0; c < 2; ++c) {
            const float4 x0 = *reinterpret_cast<const float4*>(kp + c * 32);
            const float4 x1 = *reinterpret_cast<const float4*>(kp + c * 32 + 4);
            f16x8& kb = c ? kb1 : kb0;
            kb[0] = (_Float16)x0.x; kb[1] = (_Float16)x0.y;
            kb[2] = (_Float16)x0.z; kb[3] = (_Float16)x0.w;
            kb[4] = (_Float16)x1.x; kb[5] = (_Float16)x1.y;
            kb[6] = (_Float16)x1.z; kb[7] = (_Float16)x1.w;
        }
        f32x4 acc = {0.f, 0.f, 0.f, 0.f};
        acc = __builtin_amdgcn_mfma_f32_16x16x32_f16(kb0, qa[0], acc, 0, 0, 0);
        acc = __builtin_amdgcn_mfma_f32_16x16x32_f16(kb1, qa[1], acc, 0, 0, 0);
        const float4 ma = *reinterpret_cast<const float4*>(madd_sh + key0 + grp * 4);
        f16x4 st;
        #pragma unroll
        for (int r = 0; r < 4; ++r)
            st[r] = (_Float16)fmaxf(acc[r] + (&ma.x)[r], -60000.0f);
        *reinterpret_cast<f16x4*>(&s_sh[row * 2048 + swz2l(row, key0 + grp * 4)]) = st;
    }
    __syncthreads();

    {
        const int q = w;
        const _Float16* zrow = &s_sh[q * 2048];
        f16x8 m8 = *reinterpret_cast<const f16x8*>(&zrow[swz2l(q, lane * 32)]);
        #pragma unroll
        for (int j = 1; j < 4; ++j) {
            const f16x8 zv = *reinterpret_cast<const f16x8*>(&zrow[swz2l(q, lane * 32 + j * 8)]);
            m8 = __builtin_elementwise_max(m8, zv);
        }
        float m = (float)m8[0];
        #pragma unroll
        for (int e = 1; e < 8; ++e) m = fmaxf(m, (float)m8[e]);
        #pragma unroll
        for (int off = 32; off >= 1; off >>= 1) m = fmaxf(m, __shfl_xor(m, off));
        const float thr = m - 1.0f;
        float tau = thr;
        #pragma unroll 1
        for (int it = 0; it < 32; ++it) {
            float s = 0.f, c = 0.f;
            #pragma unroll
            for (int j = 0; j < 4; ++j) {
                const f16x8 zv = *reinterpret_cast<const f16x8*>(&zrow[swz2l(q, lane * 32 + j * 8)]);
                #pragma unroll
                for (int e = 0; e < 8; ++e) {
                    const float d = (float)zv[e] - tau;
                    s += fmaxf(d, 0.f);
                    c += (d > 0.f ? 1.f : 0.f);
                }
            }
            #pragma unroll
            for (int off = 32; off >= 1; off >>= 1) {
                s += __shfl_xor(s, off);
                c += __shfl_xor(c, off);
            }
            const float tn = tau + (s - 1.0f) / c;
            if (!(tn > tau)) break;
            tau = tn;
        }
        if (lane == 0) tau_s[q] = tau;
    }
    __syncthreads();

    const float tau_row = tau_s[row];
    f16x8 t8;
    {
        const _Float16 th = (_Float16)tau_row;
        #pragma unroll
        for (int e = 0; e < 8; ++e) t8[e] = th;
    }
    f32x4 o[4] = {{0.f,0.f,0.f,0.f},{0.f,0.f,0.f,0.f},{0.f,0.f,0.f,0.f},{0.f,0.f,0.f,0.f}};
    for (int c = w * 4; c < w * 4 + 4; ++c) {
        const int k0 = c * 32;
        const f16x8 zv = *reinterpret_cast<const f16x8*>(
            &s_sh[row * 2048 + swz2l(row, k0 + grp * 8)]);
        const f16x8 pa2 = __builtin_elementwise_max(zv - t8, (f16x8)(_Float16)0.0f);
        #pragma unroll
        for (int n = 0; n < 4; ++n) {
            f16x8 vb;
            #pragma unroll
            for (int j = 0; j < 8; ++j)
                vb[j] = (_Float16)V[bhSD + (size_t)(k0 + grp * 8 + j) * D + n * 16 + row];
            o[n] = __builtin_amdgcn_mfma_f32_16x16x32_f16(pa2, vb, o[n], 0, 0, 0);
        }
    }
    __syncthreads();

    float* red = reinterpret_cast<float*>(s_sh);
    #pragma unroll
    for (int n = 0; n < 4; ++n)
        #pragma unroll
        for (int r = 0; r < 4; ++r)
            red[w * 1024 + (grp * 4 + r) * 64 + n * 16 + row] = o[n][r];
    __syncthreads();

    {
        const int q = tid >> 6;
        const int d = tid & 63;
        float sum = 0.f;
        #pragma unroll
        for (int p = 0; p < 16; ++p)
            sum += red[p * 1024 + q * 64 + d];
        out[bhSD + (size_t)(q0 + q) * D + d] = sum;
    }
}

extern "C" void kernel_launch(void* const* d_in, const int* in_sizes, int n_in,
                              void* d_out, int out_size, void* d_ws, size_t ws_size,
                              hipStream_t stream) {
    const float* Q     = (const float*)d_in[0];
    const float* K     = (const float*)d_in[1];
    const float* V     = (const float*)d_in[2];
    const float* mask  = (const float*)d_in[3];
    const float* scale = (const float*)d_in[4];
    float* out = (float*)d_out;

    const int BH = B * H;
    const size_t need = 2 * BHSD * sizeof(_Float16);   // Qht + Kht = 12.6 MB

    if (ws_size >= need) {
        _Float16* Qht = (_Float16*)d_ws;
        _Float16* Kht = Qht + BHSD;
        cvt_tiled_kernel<true ><<<dim3(BH * 64), dim3(256), 0, stream>>>(Q, scale, Qht);
        cvt_tiled_kernel<false><<<dim3(BH * 64), dim3(256), 0, stream>>>(K, scale, Kht);
        spmax_cand_kernel<<<dim3(BH * 128), dim3(256), 0, stream>>>(
            Qht, Kht, mask, Q, K, V, scale, out);
    } else {
        sparsemax_fused_fallback<<<dim3(BH * NBLK_Q), dim3(1024), 0, stream>>>(
            Q, K, V, mask, scale, out);
    }
}